// Round 4
// baseline (633.946 us; speedup 1.0000x reference)
//
#include <hip/hip_runtime.h>
#include <math.h>

#define B_ 1024
#define D_ 1024
#define N_ 128
#define PT_ 28
#define KSEL 32            // softmax over top 32 (k=33, last dropped)
#define NOISE_EPS_ 0.01f

typedef float v4f __attribute__((ext_vector_type(4)));

// ---------------- Kernel A: unique t_embed rows ue[28][1024] (fp32) ---------
// grid (28, 4) x 256 threads. block (s, y) computes ue[s][y*256 + tid].
__global__ __launch_bounds__(256) void embed_kernel(
    const float* __restrict__ w1, const float* __restrict__ b1,
    const float* __restrict__ w2, const float* __restrict__ b2,
    float* __restrict__ ue)
{
    __shared__ float h[D_];
    const int s = blockIdx.x;
    const int tid = threadIdx.x;
    const float sf = (float)s;
    for (int d = tid; d < D_; d += 256) {
        float x = sf * w1[d] + b1[d];          // t @ w1.T + b1  (w1 is [D,1])
        h[d] = x / (1.0f + expf(-x));          // SiLU
    }
    __syncthreads();
    const int i = blockIdx.y * 256 + tid;
    const v4f* row = (const v4f*)(w2 + (size_t)i * D_);   // w2[i, :]
    float acc = 0.0f;
    for (int d = 0; d < D_ / 4; ++d) {
        v4f u = row[d];
        const int d4 = d * 4;
        acc += h[d4 + 0] * u.x + h[d4 + 1] * u.y + h[d4 + 2] * u.z + h[d4 + 3] * u.w;
    }
    ue[(size_t)s * D_ + i] = acc + b2[i];
}

// ------- Kernel B: unique clean logits + noise_std, uclean/unstd[28][128] ---
__global__ __launch_bounds__(256) void gate_precompute_kernel(
    const float* __restrict__ gate_w, const float* __restrict__ gate_b,
    const float* __restrict__ w_noise, const int* __restrict__ timestep,
    const float* __restrict__ ue, float* __restrict__ uclean, float* __restrict__ unstd)
{
    __shared__ float te[D_];
    __shared__ float pc[2][N_];
    __shared__ float pn[2][N_];
    const int s = blockIdx.x;
    const int tid = threadIdx.x;
    for (int d = tid; d < D_; d += 256) te[d] = ue[(size_t)s * D_ + d];
    __syncthreads();
    const int n = tid & (N_ - 1);
    const int half = tid >> 7;
    const int d0 = half * (D_ / 2);
    const float* grow = gate_w + (size_t)n * (D_ + 1) + d0;   // gate_w[n, d0..]
    float cl = 0.0f, nz = 0.0f;
    for (int d = 0; d < D_ / 2; ++d) {
        float tv = te[d0 + d];
        cl += tv * grow[d];
        nz += tv * w_noise[(size_t)(d0 + d) * N_ + n];        // w_noise[d, n]
    }
    pc[half][n] = cl; pn[half][n] = nz;
    __syncthreads();
    if (tid < N_) {
        const int step = timestep[0];
        float cl2 = pc[0][tid] + pc[1][tid]
                  + (float)step * gate_w[(size_t)tid * (D_ + 1) + D_]   // depth col
                  + gate_b[tid];
        uclean[s * N_ + tid] = cl2;
        float nz2 = pn[0][tid] + pn[1][tid];
        float sp = (nz2 > 20.0f) ? nz2 : log1pf(expf(nz2));   // softplus
        unstd[s * N_ + tid] = sp + NOISE_EPS_;
    }
}

// ------- Kernel C: per-row gates[B][128] + out1 (t_embed gather) ------------
// grid B x 128 threads (2 waves). Wave-shuffle softmax sum.
__global__ __launch_bounds__(128) void gates_kernel(
    const float* __restrict__ noise, const int* __restrict__ timestep,
    const float* __restrict__ ue, const float* __restrict__ uclean,
    const float* __restrict__ unstd,
    float* __restrict__ gw_out, float* __restrict__ out1)
{
    __shared__ float noisy[N_];
    __shared__ float psum[2];
    const int b = blockIdx.x;
    const int tid = threadIdx.x;           // 0..127
    const int tb = timestep[b];

    // out1: t_embed[b,:] = ue[tb,:]  (256 float4 / 128 threads = 2 iters)
    const v4f* uev = (const v4f*)(ue + (size_t)tb * D_);
    v4f* o1v = (v4f*)(out1 + (size_t)b * D_);
    o1v[tid]       = uev[tid];
    o1v[tid + 128] = uev[tid + 128];

    const float v = uclean[tb * N_ + tid]
                  + noise[(size_t)b * N_ + tid] * unstd[tb * N_ + tid];
    noisy[tid] = v;
    __syncthreads();

    int rank = 0; float mx = -INFINITY;
    #pragma unroll 8
    for (int m = 0; m < N_; ++m) {
        float u = noisy[m];
        mx = fmaxf(mx, u);
        rank += ((u > v) || (u == v && m < tid)) ? 1 : 0;   // lax.top_k tie-break
    }
    float g = (rank < KSEL) ? expf(v - mx) : 0.0f;

    // sum across 128 threads: 64-lane butterfly leaves full wave-sum in
    // every lane; one lane per wave posts it, then combine the two waves.
    float s = g;
    #pragma unroll
    for (int off = 32; off > 0; off >>= 1) s += __shfl_xor(s, off);
    if ((tid & 63) == 0) psum[tid >> 6] = s;
    __syncthreads();
    const float inv = 1.0f / (psum[0] + psum[1]);
    gw_out[(size_t)b * N_ + tid] = g * inv;
}

// ------- Kernel D: pure streamer out0[b,n,:] = prompts[step,n,:]*g[b,n] -----
// grid 4096 x 256; 32 float4 per thread; nontemporal stores.
__global__ __launch_bounds__(256) void stream_kernel(
    const float* __restrict__ pe, const int* __restrict__ timestep,
    const float* __restrict__ gw, float* __restrict__ out0)
{
    const int step = timestep[0];
    const v4f* __restrict__ psrc = (const v4f*)(pe + (size_t)step * N_ * D_);
    v4f* __restrict__ dst = (v4f*)out0;
    int f = blockIdx.x * 8192 + threadIdx.x;       // total 4096*8192 = 2^25 v4f
    #pragma unroll 4
    for (int it = 0; it < 32; ++it, f += 256) {
        const int r = f & 32767;                   // index within one b-row
        const int b = f >> 15;
        const int n = r >> 8;
        const float g = gw[(b << 7) | n];
        v4f o;
        if (g != 0.0f) {
            v4f u = psrc[r];
            o = u * g;
        } else {
            o = (v4f)(0.0f);
        }
        __builtin_nontemporal_store(o, dst + f);
    }
}

extern "C" void kernel_launch(void* const* d_in, const int* in_sizes, int n_in,
                              void* d_out, int out_size, void* d_ws, size_t ws_size,
                              hipStream_t stream) {
    (void)in_sizes; (void)n_in; (void)out_size; (void)ws_size;
    const float* pe      = (const float*)d_in[0];
    const float* w1      = (const float*)d_in[1];
    const float* b1      = (const float*)d_in[2];
    const float* w2      = (const float*)d_in[3];
    const float* b2      = (const float*)d_in[4];
    const float* gate_w  = (const float*)d_in[5];
    const float* gate_b  = (const float*)d_in[6];
    const float* w_noise = (const float*)d_in[7];
    const float* noise   = (const float*)d_in[8];
    const int*   ts      = (const int*)d_in[9];

    float* ws     = (float*)d_ws;
    float* ue     = ws;                         // 28*1024
    float* uclean = ue + PT_ * D_;              // 28*128
    float* unstd  = uclean + PT_ * N_;          // 28*128
    float* gw     = unstd + PT_ * N_;           // 1024*128

    float* out0 = (float*)d_out;                       // [B,N,D]
    float* out1 = out0 + (size_t)B_ * N_ * D_;         // [B,D]

    hipLaunchKernelGGL(embed_kernel, dim3(PT_, 4), dim3(256), 0, stream,
                       w1, b1, w2, b2, ue);
    hipLaunchKernelGGL(gate_precompute_kernel, dim3(PT_), dim3(256), 0, stream,
                       gate_w, gate_b, w_noise, ts, ue, uclean, unstd);
    hipLaunchKernelGGL(gates_kernel, dim3(B_), dim3(128), 0, stream,
                       noise, ts, ue, uclean, unstd, gw, out1);
    hipLaunchKernelGGL(stream_kernel, dim3(4096), dim3(256), 0, stream,
                       pe, ts, gw, out0);
}